// Round 7
// baseline (2886.321 us; speedup 1.0000x reference)
//
#include <hip/hip_runtime.h>
#include <stdint.h>

#define T_STEPS 784
#define H 256
#define NBLK 256        // 2 samples per block, 1 block/CU
#define NTHR 512        // 8 waves; wave w: VGPR rows [192+8w,200+8w), resid rows [24w,24w+24)

typedef unsigned long long u64;
typedef unsigned int u32;

// Per-neuron mask parameters, replicating numpy linspace/ceil/round in float64.
__device__ __forceinline__ void mask_params(int j, int& c, int& on, int& ps) {
    const double stepc = (8.0 - 4.0) / 255.0;
    const double stepd = (0.9 - 0.1) / 255.0;
    const double stepp = 4.0 / 255.0;
    double cyc = (j == 255) ? 8.0 : __dadd_rn(__dmul_rn((double)j, stepc), 4.0);
    c = (int)ceil(cyc);
    double dc  = (j == 255) ? 0.9 : __dadd_rn(__dmul_rn((double)j, stepd), 0.1);
    on = (int)ceil(__dmul_rn(dc, (double)c));
    double psd = (j == 255) ? 4.0 : __dmul_rn((double)j, stepp);
    ps = (int)rint(psd);
}

__device__ __forceinline__ u64 rfl64(u64 v) {
    unsigned int lo = __builtin_amdgcn_readfirstlane((unsigned int)v);
    unsigned int hi = __builtin_amdgcn_readfirstlane((unsigned int)(v >> 32));
    return ((u64)hi << 32) | lo;
}

// Extract 24-bit window [off, off+24) of (hi:lo). off in [0,40].
__device__ __forceinline__ u64 win24(u64 lo, u64 hi, int off) {
    u64 v = off ? ((lo >> off) | (hi << (64 - off))) : lo;
    return v & 0xFFFFFFull;
}

__device__ __forceinline__ void fmac4(float4& a, float f, const float4& w) {
    a.x = fmaf(f, w.x, a.x); a.y = fmaf(f, w.y, a.y);
    a.z = fmaf(f, w.z, a.z); a.w = fmaf(f, w.w, a.w);
}

// Sparse union consume of 24 residual rows at base (row k -> base + k*1KB).
// q0,q1: scalar (wave-uniform) 24-bit activity windows for samples 0/1.
// 8-deep load batching, static indices only; SGPR-select f in {0,1}.
#define GRABK(kk) int kk = (int)__builtin_ctzll(u); u &= u - 1
#define LDR(wv, kk) float4 wv = *(const float4*)(base + ((kk) << 10) + l16)
#define APPL(wv, kk) { \
    float f0 = ((q0 >> (kk)) & 1ull) ? 1.0f : 0.0f; \
    float f1 = ((q1 >> (kk)) & 1ull) ? 1.0f : 0.0f; \
    fmac4(a0, f0, wv); fmac4(a1, f1, wv); }

__device__ __forceinline__ void cons_resid(const char* __restrict__ base, int l16,
                                           u64 q0, u64 q1, float4& a0, float4& a1)
{
    u64 u = q0 | q1;
    int n = __popcll(u);
    while (n >= 8) {
        GRABK(k0); GRABK(k1); GRABK(k2); GRABK(k3);
        GRABK(k4); GRABK(k5); GRABK(k6); GRABK(k7);
        LDR(w0,k0); LDR(w1,k1); LDR(w2,k2); LDR(w3,k3);
        LDR(w4,k4); LDR(w5,k5); LDR(w6,k6); LDR(w7,k7);
        APPL(w0,k0); APPL(w1,k1); APPL(w2,k2); APPL(w3,k3);
        APPL(w4,k4); APPL(w5,k5); APPL(w6,k6); APPL(w7,k7);
        n -= 8;
    }
    if (n & 4) {
        GRABK(k0); GRABK(k1); GRABK(k2); GRABK(k3);
        LDR(w0,k0); LDR(w1,k1); LDR(w2,k2); LDR(w3,k3);
        APPL(w0,k0); APPL(w1,k1); APPL(w2,k2); APPL(w3,k3);
    }
    if (n & 2) {
        GRABK(k0); GRABK(k1);
        LDR(w0,k0); LDR(w1,k1);
        APPL(w0,k0); APPL(w1,k1);
    }
    if (n & 1) {
        GRABK(k0);
        LDR(w0,k0);
        APPL(w0,k0);
    }
}

__device__ __forceinline__ void upd(float& mem, float& sp, float h, int mbit) {
    float nm = fmaf(mem * 0.5f, (1.0f - sp), h);
    mem = mbit ? nm : mem;
    sp  = (mbit && (mem > 0.5f)) ? 1.0f : 0.0f;
}

// Tiled transpose of the 4 weight matrices into ws: WT[k][j] = W[j][k].
__global__ __launch_bounds__(256)
void prep_transpose(const float* __restrict__ w1, const float* __restrict__ w2a,
                    const float* __restrict__ w2b, const float* __restrict__ w3,
                    float* __restrict__ ws)
{
    __shared__ float tile[64][65];
    const int bid = blockIdx.x;                 // 64 blocks: m(4) x kt(4) x jt(4)
    const int m  = bid >> 4;
    const int kt = (bid >> 2) & 3;
    const int jt = bid & 3;
    const float* src = (m == 0) ? w1 : (m == 1) ? w2a : (m == 2) ? w2b : w3;
    float* dst = ws + (size_t)m * H * H;
    const int tid = threadIdx.x;
    const int c = tid & 63, r4 = tid >> 6;
    #pragma unroll
    for (int rr = 0; rr < 16; rr++) {
        int r = r4 * 16 + rr;
        tile[r][c] = src[(size_t)(jt * 64 + r) * H + kt * 64 + c];
    }
    __syncthreads();
    #pragma unroll
    for (int rr = 0; rr < 16; rr++) {
        int r = r4 * 16 + rr;
        dst[(size_t)(kt * 64 + r) * H + jt * 64 + c] = tile[c][r];
    }
}

#define PEXI(w,l,s,q) (((w) << 9) + ((l) << 3) + ((s) << 2) + (q))

__global__ __launch_bounds__(NTHR, 2)
void srnn_kernel(const float* __restrict__ x,
                 const float* __restrict__ w_i2h1, const float* __restrict__ b_i2h1,
                 const float* __restrict__ b_h2h1,
                 const float* __restrict__ b_i2h2, const float* __restrict__ b_h2h2,
                 const float* __restrict__ b_i2h3,
                 const float* __restrict__ w_h2o3, const float* __restrict__ b_h2o3,
                 const float* __restrict__ ws,     // WT1 | WT2a | WT2b | WT3
                 float* __restrict__ out)
{
    const int tid  = threadIdx.x;
    const int lane = tid & 63;
    const int w    = tid >> 6;          // wave id
    const int l16  = lane * 16;
    const int s_up = tid >> 8;          // upd role: sample 0/1
    const int j    = tid & 255;         // upd role: neuron
    const int word = (tid >> 6) & 3;    // upd role: ballot word
    const int s_base = blockIdx.x * 2;

    const char* wt1  = (const char*)ws;
    const char* wt2a = (const char*)ws + (1 << 18);
    const char* wt2b = (const char*)ws + (2 << 18);
    const char* wt3  = (const char*)ws + (3 << 18);

    // Residual slice for this wave: rows [24w, 24w+24) of each matrix.
    const int rk0 = 24 * w;
    const char* r1  = wt1  + (rk0 << 10);
    const char* r2a = wt2a + (rk0 << 10);
    const char* r2b = wt2b + (rk0 << 10);
    const char* r3  = wt3  + (rk0 << 10);
    const int rsel = rk0 >> 6, roff = rk0 & 63;   // window word/offset

    // VGPR-resident rows: [192+8w, 200+8w) of each matrix (high mask-duty).
    const int vk0 = 192 + 8 * w;
    float4 vwA[8], vwB[8], vwC[8], vwD[8];
    #pragma unroll
    for (int r = 0; r < 8; r++) {
        vwA[r] = *(const float4*)(wt1  + ((vk0 + r) << 10) + l16);
        vwB[r] = *(const float4*)(wt2a + ((vk0 + r) << 10) + l16);
        vwC[r] = *(const float4*)(wt2b + ((vk0 + r) << 10) + l16);
        vwD[r] = *(const float4*)(wt3  + ((vk0 + r) << 10) + l16);
    }

    __shared__ float xls[2][T_STEPS];       // 6.3 KB
    __shared__ u64 um1[2][4];               // spike ballots [s][word]
    __shared__ u64 um2[2][4];
    __shared__ float spk1f[2][H];           // float spikes (VGPR-row gates), 2 KB
    __shared__ float spk2f[2][H];
    __shared__ float pexA[8 * 512];         // [w][lane][s][q] partials, 16 KB
    __shared__ float pexB[8 * 512];
    __shared__ float pexC[8 * 512];
    __shared__ float wred[8][10];

    for (int i = tid; i < 2 * T_STEPS; i += NTHR) {
        int s = i / T_STEPS, t = i - s * T_STEPS;
        xls[s][t] = x[(size_t)(s_base + s) * T_STEPS + t];
    }
    if (tid < 16) { ((u64*)um1)[tid & 7] = 0ull; ((u64*)um2)[tid & 7] = 0ull; }
    for (int i = tid; i < 2 * H; i += NTHR) {
        ((float*)spk1f)[i] = 0.0f; ((float*)spk2f)[i] = 0.0f;
    }

    int mc, mon, mps;
    mask_params(j, mc, mon, mps);
    int ph = (mc - (mps % mc)) % mc;

    const float bs1 = b_i2h1[j] + b_h2h1[j];
    const float bs2 = b_i2h2[j] + b_h2h2[j];
    const float bs3 = b_i2h3[j];
    const float wi1 = w_i2h1[j];

    float mem1 = 0.f, mem2 = 0.f, mem3 = 0.f;
    float sp1 = 0.f, sp2 = 0.f, sp3 = 0.f;
    float cnt = 0.f;                         // sum_t spk3 (out = wo·cnt exact)

    __syncthreads();

    for (int t = 0; t < T_STEPS; t++) {
        const int mbit = (ph < mon) ? 1 : 0;

        // ======== phase a: W1, gated by layer-1 spikes of t-1 ========
        {
            float4 a0 = {0,0,0,0}, a1 = {0,0,0,0};
            // VGPR rows (float gates, broadcast from LDS)
            const float4* f0p = (const float4*)&spk1f[0][vk0];
            const float4* f1p = (const float4*)&spk1f[1][vk0];
            float4 f0a = f0p[0], f0b = f0p[1], f1a = f1p[0], f1b = f1p[1];
            fmac4(a0, f0a.x, vwA[0]); fmac4(a1, f1a.x, vwA[0]);
            fmac4(a0, f0a.y, vwA[1]); fmac4(a1, f1a.y, vwA[1]);
            fmac4(a0, f0a.z, vwA[2]); fmac4(a1, f1a.z, vwA[2]);
            fmac4(a0, f0a.w, vwA[3]); fmac4(a1, f1a.w, vwA[3]);
            fmac4(a0, f0b.x, vwA[4]); fmac4(a1, f1b.x, vwA[4]);
            fmac4(a0, f0b.y, vwA[5]); fmac4(a1, f1b.y, vwA[5]);
            fmac4(a0, f0b.z, vwA[6]); fmac4(a1, f1b.z, vwA[6]);
            fmac4(a0, f0b.w, vwA[7]); fmac4(a1, f1b.w, vwA[7]);
            // residual rows from L2 (union of both samples)
            u64 q0 = win24(rfl64(um1[0][rsel]), rfl64(um1[0][rsel + 1]), roff);
            u64 q1 = win24(rfl64(um1[1][rsel]), rfl64(um1[1][rsel + 1]), roff);
            cons_resid(r1, l16, q0, q1, a0, a1);
            *(float4*)&pexA[PEXI(w, lane, 0, 0)] = a0;
            *(float4*)&pexA[PEXI(w, lane, 1, 0)] = a1;
        }
        __syncthreads();                                     // B1

        // ---- upd1: publish um1 + spk1f
        {
            float hs = 0.f;
            #pragma unroll
            for (int ww = 0; ww < 8; ww++) hs += pexA[PEXI(ww, j >> 2, s_up, j & 3)];
            float h1 = hs + fmaf(xls[s_up][t], wi1, bs1);
            upd(mem1, sp1, h1, mbit);
            u64 bl = __ballot(sp1 != 0.0f);
            if (lane == 0) um1[s_up][word] = bl;
            spk1f[s_up][j] = sp1;
        }
        __syncthreads();                                     // B2

        // ======== phase c: W2a (fresh spk1) + W2b (old spk2) ========
        {
            float4 a0 = {0,0,0,0}, a1 = {0,0,0,0};
            {
                const float4* f0p = (const float4*)&spk1f[0][vk0];
                const float4* f1p = (const float4*)&spk1f[1][vk0];
                float4 f0a = f0p[0], f0b = f0p[1], f1a = f1p[0], f1b = f1p[1];
                fmac4(a0, f0a.x, vwB[0]); fmac4(a1, f1a.x, vwB[0]);
                fmac4(a0, f0a.y, vwB[1]); fmac4(a1, f1a.y, vwB[1]);
                fmac4(a0, f0a.z, vwB[2]); fmac4(a1, f1a.z, vwB[2]);
                fmac4(a0, f0a.w, vwB[3]); fmac4(a1, f1a.w, vwB[3]);
                fmac4(a0, f0b.x, vwB[4]); fmac4(a1, f1b.x, vwB[4]);
                fmac4(a0, f0b.y, vwB[5]); fmac4(a1, f1b.y, vwB[5]);
                fmac4(a0, f0b.z, vwB[6]); fmac4(a1, f1b.z, vwB[6]);
                fmac4(a0, f0b.w, vwB[7]); fmac4(a1, f1b.w, vwB[7]);
            }
            {
                const float4* f0p = (const float4*)&spk2f[0][vk0];
                const float4* f1p = (const float4*)&spk2f[1][vk0];
                float4 f0a = f0p[0], f0b = f0p[1], f1a = f1p[0], f1b = f1p[1];
                fmac4(a0, f0a.x, vwC[0]); fmac4(a1, f1a.x, vwC[0]);
                fmac4(a0, f0a.y, vwC[1]); fmac4(a1, f1a.y, vwC[1]);
                fmac4(a0, f0a.z, vwC[2]); fmac4(a1, f1a.z, vwC[2]);
                fmac4(a0, f0a.w, vwC[3]); fmac4(a1, f1a.w, vwC[3]);
                fmac4(a0, f0b.x, vwC[4]); fmac4(a1, f1b.x, vwC[4]);
                fmac4(a0, f0b.y, vwC[5]); fmac4(a1, f1b.y, vwC[5]);
                fmac4(a0, f0b.z, vwC[6]); fmac4(a1, f1b.z, vwC[6]);
                fmac4(a0, f0b.w, vwC[7]); fmac4(a1, f1b.w, vwC[7]);
            }
            {
                u64 q0 = win24(rfl64(um1[0][rsel]), rfl64(um1[0][rsel + 1]), roff);
                u64 q1 = win24(rfl64(um1[1][rsel]), rfl64(um1[1][rsel + 1]), roff);
                cons_resid(r2a, l16, q0, q1, a0, a1);
            }
            {
                u64 q0 = win24(rfl64(um2[0][rsel]), rfl64(um2[0][rsel + 1]), roff);
                u64 q1 = win24(rfl64(um2[1][rsel]), rfl64(um2[1][rsel + 1]), roff);
                cons_resid(r2b, l16, q0, q1, a0, a1);
            }
            *(float4*)&pexB[PEXI(w, lane, 0, 0)] = a0;
            *(float4*)&pexB[PEXI(w, lane, 1, 0)] = a1;
        }
        __syncthreads();                                     // B3

        // ---- upd2: publish um2 + spk2f
        {
            float hs = 0.f;
            #pragma unroll
            for (int ww = 0; ww < 8; ww++) hs += pexB[PEXI(ww, j >> 2, s_up, j & 3)];
            upd(mem2, sp2, hs + bs2, mbit);
            u64 bl = __ballot(sp2 != 0.0f);
            if (lane == 0) um2[s_up][word] = bl;
            spk2f[s_up][j] = sp2;
        }
        __syncthreads();                                     // B4

        // ======== phase e: W3, gated by fresh spk2 ========
        {
            float4 a0 = {0,0,0,0}, a1 = {0,0,0,0};
            const float4* f0p = (const float4*)&spk2f[0][vk0];
            const float4* f1p = (const float4*)&spk2f[1][vk0];
            float4 f0a = f0p[0], f0b = f0p[1], f1a = f1p[0], f1b = f1p[1];
            fmac4(a0, f0a.x, vwD[0]); fmac4(a1, f1a.x, vwD[0]);
            fmac4(a0, f0a.y, vwD[1]); fmac4(a1, f1a.y, vwD[1]);
            fmac4(a0, f0a.z, vwD[2]); fmac4(a1, f1a.z, vwD[2]);
            fmac4(a0, f0a.w, vwD[3]); fmac4(a1, f1a.w, vwD[3]);
            fmac4(a0, f0b.x, vwD[4]); fmac4(a1, f1b.x, vwD[4]);
            fmac4(a0, f0b.y, vwD[5]); fmac4(a1, f1b.y, vwD[5]);
            fmac4(a0, f0b.z, vwD[6]); fmac4(a1, f1b.z, vwD[6]);
            fmac4(a0, f0b.w, vwD[7]); fmac4(a1, f1b.w, vwD[7]);
            u64 q0 = win24(rfl64(um2[0][rsel]), rfl64(um2[0][rsel + 1]), roff);
            u64 q1 = win24(rfl64(um2[1][rsel]), rfl64(um2[1][rsel + 1]), roff);
            cons_resid(r3, l16, q0, q1, a0, a1);
            *(float4*)&pexC[PEXI(w, lane, 0, 0)] = a0;
            *(float4*)&pexC[PEXI(w, lane, 1, 0)] = a1;
        }
        __syncthreads();                                     // B5

        // ---- upd3: layer-3 state private; count spikes (out = wo·cnt at end)
        {
            float hs = 0.f;
            #pragma unroll
            for (int ww = 0; ww < 8; ww++) hs += pexC[PEXI(ww, j >> 2, s_up, j & 3)];
            upd(mem3, sp3, hs + bs3, mbit);
            cnt += sp3;
        }
        // no barrier: next phase-a writes pexA (last read upd1, 3 barriers back)
        // and reads um1/spk1f (stable since upd1 of this step).

        ph++; if (ph == mc) ph = 0;
    }

    // ---- output: out[s][i] = (sum_j w_h2o3[i][j]*cnt_j)/784 + b[i]
    #pragma unroll
    for (int i = 0; i < 10; i++) {
        float v = cnt * w_h2o3[i * H + j];
        for (int off = 32; off; off >>= 1) v += __shfl_down(v, off, 64);
        if (lane == 0) wred[w][i] = v;
    }
    __syncthreads();
    if (tid < 20) {
        int s = tid / 10, i = tid % 10;
        float sum = wred[s*4 + 0][i] + wred[s*4 + 1][i] + wred[s*4 + 2][i] + wred[s*4 + 3][i];
        out[(size_t)(s_base + s) * 10 + i] = sum / 784.0f + b_h2o3[i];
    }
}

extern "C" void kernel_launch(void* const* d_in, const int* in_sizes, int n_in,
                              void* d_out, int out_size, void* d_ws, size_t ws_size,
                              hipStream_t stream) {
    (void)in_sizes; (void)n_in; (void)ws_size; (void)out_size;
    const float* x      = (const float*)d_in[0];
    const float* w_i2h1 = (const float*)d_in[1];
    const float* b_i2h1 = (const float*)d_in[2];
    const float* w_h2h1 = (const float*)d_in[3];
    const float* b_h2h1 = (const float*)d_in[4];
    const float* w_i2h2 = (const float*)d_in[5];
    const float* b_i2h2 = (const float*)d_in[6];
    const float* w_h2h2 = (const float*)d_in[7];
    const float* b_h2h2 = (const float*)d_in[8];
    const float* w_i2h3 = (const float*)d_in[9];
    const float* b_i2h3 = (const float*)d_in[10];
    const float* w_h2o3 = (const float*)d_in[11];
    const float* b_h2o3 = (const float*)d_in[12];
    float* ws = (float*)d_ws;   // 4 * 256 KB = 1 MB

    prep_transpose<<<64, 256, 0, stream>>>(w_h2h1, w_i2h2, w_h2h2, w_i2h3, ws);
    srnn_kernel<<<NBLK, NTHR, 0, stream>>>(x,
        w_i2h1, b_i2h1, b_h2h1,
        b_i2h2, b_h2h2, b_i2h3,
        w_h2o3, b_h2o3, ws,
        (float*)d_out);
}

// Round 8
// 2260.467 us; speedup vs baseline: 1.2769x; 1.2769x over previous
//
#include <hip/hip_runtime.h>
#include <stdint.h>

#define T_STEPS 784
#define H 256
#define NBLK 512        // 1 sample per block, 2 blocks/CU
#define NTHR 256        // 4 waves; wave w owns neurons AND rows [64w, 64w+64)

typedef unsigned long long u64;
typedef unsigned int u32;

// Per-neuron mask parameters, replicating numpy linspace/ceil/round in float64.
__device__ __forceinline__ void mask_params(int j, int& c, int& on, int& ps) {
    const double stepc = (8.0 - 4.0) / 255.0;
    const double stepd = (0.9 - 0.1) / 255.0;
    const double stepp = 4.0 / 255.0;
    double cyc = (j == 255) ? 8.0 : __dadd_rn(__dmul_rn((double)j, stepc), 4.0);
    c = (int)ceil(cyc);
    double dc  = (j == 255) ? 0.9 : __dadd_rn(__dmul_rn((double)j, stepd), 0.1);
    on = (int)ceil(__dmul_rn(dc, (double)c));
    double psd = (j == 255) ? 4.0 : __dmul_rn((double)j, stepp);
    ps = (int)rint(psd);
}

__device__ __forceinline__ void acc_add(const float4& w, float4& a) {
    a.x += w.x; a.y += w.y; a.z += w.z; a.w += w.w;
}

// Sparse accumulate over this wave's 64 rows. m: wave's own spike ballot (SGPR,
// loop-carried in registers). base: rows [64w..64w+64) (row k -> 1KB apart);
// lane covers 4 cols via l16. 8-deep load batching; binary tail.
__device__ __forceinline__ void consume64(const char* __restrict__ base, u64 m,
                                          int l16, float4& acc) {
    int n = __popcll(m);
    while (n >= 8) {
        int k0=__builtin_ctzll(m); m&=m-1; int k1=__builtin_ctzll(m); m&=m-1;
        int k2=__builtin_ctzll(m); m&=m-1; int k3=__builtin_ctzll(m); m&=m-1;
        int k4=__builtin_ctzll(m); m&=m-1; int k5=__builtin_ctzll(m); m&=m-1;
        int k6=__builtin_ctzll(m); m&=m-1; int k7=__builtin_ctzll(m); m&=m-1;
        float4 w0 = *(const float4*)(base + (k0<<10) + l16);
        float4 w1 = *(const float4*)(base + (k1<<10) + l16);
        float4 w2 = *(const float4*)(base + (k2<<10) + l16);
        float4 w3 = *(const float4*)(base + (k3<<10) + l16);
        float4 w4 = *(const float4*)(base + (k4<<10) + l16);
        float4 w5 = *(const float4*)(base + (k5<<10) + l16);
        float4 w6 = *(const float4*)(base + (k6<<10) + l16);
        float4 w7 = *(const float4*)(base + (k7<<10) + l16);
        acc_add(w0, acc); acc_add(w1, acc); acc_add(w2, acc); acc_add(w3, acc);
        acc_add(w4, acc); acc_add(w5, acc); acc_add(w6, acc); acc_add(w7, acc);
        n -= 8;
    }
    if (n & 4) {
        int k0=__builtin_ctzll(m); m&=m-1; int k1=__builtin_ctzll(m); m&=m-1;
        int k2=__builtin_ctzll(m); m&=m-1; int k3=__builtin_ctzll(m); m&=m-1;
        float4 w0 = *(const float4*)(base + (k0<<10) + l16);
        float4 w1 = *(const float4*)(base + (k1<<10) + l16);
        float4 w2 = *(const float4*)(base + (k2<<10) + l16);
        float4 w3 = *(const float4*)(base + (k3<<10) + l16);
        acc_add(w0, acc); acc_add(w1, acc); acc_add(w2, acc); acc_add(w3, acc);
    }
    if (n & 2) {
        int k0=__builtin_ctzll(m); m&=m-1; int k1=__builtin_ctzll(m); m&=m-1;
        float4 w0 = *(const float4*)(base + (k0<<10) + l16);
        float4 w1 = *(const float4*)(base + (k1<<10) + l16);
        acc_add(w0, acc); acc_add(w1, acc);
    }
    if (n & 1) {
        int k0 = __builtin_ctzll(m);
        float4 w0 = *(const float4*)(base + (k0<<10) + l16);
        acc_add(w0, acc);
    }
}

__device__ __forceinline__ void upd(float& mem, float& sp, float h, int mbit) {
    float nm = fmaf(mem * 0.5f, (1.0f - sp), h);
    mem = mbit ? nm : mem;
    sp  = (mbit && (mem > 0.5f)) ? 1.0f : 0.0f;
}

// Tiled transpose of the 4 weight matrices into ws: WT[k][j] = W[j][k].
__global__ __launch_bounds__(256)
void prep_transpose(const float* __restrict__ w1, const float* __restrict__ w2a,
                    const float* __restrict__ w2b, const float* __restrict__ w3,
                    float* __restrict__ ws)
{
    __shared__ float tile[64][65];
    const int bid = blockIdx.x;                 // 64 blocks: m(4) x kt(4) x jt(4)
    const int m  = bid >> 4;
    const int kt = (bid >> 2) & 3;
    const int jt = bid & 3;
    const float* src = (m == 0) ? w1 : (m == 1) ? w2a : (m == 2) ? w2b : w3;
    float* dst = ws + (size_t)m * H * H;
    const int tid = threadIdx.x;
    const int c = tid & 63, r4 = tid >> 6;
    #pragma unroll
    for (int rr = 0; rr < 16; rr++) {
        int r = r4 * 16 + rr;
        tile[r][c] = src[(size_t)(jt * 64 + r) * H + kt * 64 + c];
    }
    __syncthreads();
    #pragma unroll
    for (int rr = 0; rr < 16; rr++) {
        int r = r4 * 16 + rr;
        dst[(size_t)(kt * 64 + r) * H + jt * 64 + c] = tile[c][r];
    }
}

__global__ __launch_bounds__(NTHR, 2)
void srnn_kernel(const float* __restrict__ x,
                 const float* __restrict__ w_i2h1, const float* __restrict__ b_i2h1,
                 const float* __restrict__ b_h2h1,
                 const float* __restrict__ b_i2h2, const float* __restrict__ b_h2h2,
                 const float* __restrict__ b_i2h3,
                 const float* __restrict__ w_h2o3, const float* __restrict__ b_h2o3,
                 const float* __restrict__ ws,     // WT1 | WT2a | WT2b | WT3
                 float* __restrict__ out)
{
    const int tid  = threadIdx.x;
    const int lane = tid & 63;
    const int w    = tid >> 6;         // wave id = j-group = row-group
    const int j    = w * 64 + lane;    // this thread's neuron (== tid)
    const int l16  = lane * 16;        // byte offset into each row (4 cols/lane)
    const int s    = blockIdx.x;       // sample

    // Wave's row-slice base per matrix: rows [64w, 64w+64), 64KB per slice.
    const char* wt1  = (const char*)ws + (0 << 18) + (w << 16);
    const char* wt2a = (const char*)ws + (1 << 18) + (w << 16);
    const char* wt2b = (const char*)ws + (2 << 18) + (w << 16);
    const char* wt3  = (const char*)ws + (3 << 18) + (w << 16);

    __shared__ float xls[T_STEPS];          // 3.1 KB
    __shared__ float pexA[4][H];            // per-wave partials, 4 KB each
    __shared__ float pexB[4][H];
    __shared__ float pexC[4][H];
    __shared__ u64 blk[T_STEPS];            // per-step active float4-block mask, 6.3 KB
    __shared__ float wred[4][10];

    for (int i = tid; i < T_STEPS; i += NTHR)
        xls[i] = x[(size_t)s * T_STEPS + i];

    int mc, mon, mps;
    mask_params(j, mc, mon, mps);
    int ph = (mc - (mps % mc)) % mc;

    // ---- build static per-step block-active mask table (column gating).
    // blk[t] bit b == 1 iff any j in [4b,4b+4) has mask(j,t)=1. Wave w fills
    // its 16 block-bits (u16) per t; full u64 assembled by layout.
    {
        unsigned short* blk16 = (unsigned short*)blk;
        int p = ph;
        for (int t = 0; t < T_STEPS; t++) {
            u64 m = __ballot(p < mon);
            u64 bb = m | (m >> 1); bb |= (bb >> 2);            // bit 4b = block-OR
            u64 b2 = __ballot(((bb >> ((lane & 15) << 2)) & 1) != 0);
            if (lane == 0) blk16[t * 4 + w] = (unsigned short)b2;
            p++; if (p == mc) p = 0;
        }
    }

    const float bs1 = b_i2h1[j] + b_h2h1[j];
    const float bs2 = b_i2h2[j] + b_h2h2[j];
    const float bs3 = b_i2h3[j];
    const float wi1 = w_i2h1[j];

    float mem1 = 0.f, mem2 = 0.f, mem3 = 0.f;
    float sp1 = 0.f, sp2 = 0.f, sp3 = 0.f;
    u64 bal1 = 0ull, bal2 = 0ull;      // this wave's spike masks, register-resident
    float cnt = 0.f;                   // sum_t spk3; out = wo·cnt at end (exact)

    __syncthreads();

    for (int t = 0; t < T_STEPS; t++) {
        const int mbit = (ph < mon) ? 1 : 0;
        const u64 blkt = blk[t];                       // uniform broadcast read
        const u32 bhalf = (lane < 32) ? (u32)blkt : (u32)(blkt >> 32);
        const bool act = (bhalf >> (lane & 31)) & 1;   // this lane's float4-block live?

        // ---- a: L1 partials = spk1_old @ W1^T (only active column blocks)
        if (act) {
            float4 a = {0.f, 0.f, 0.f, 0.f};
            consume64(wt1, bal1, l16, a);
            ((float4*)pexA[w])[lane] = a;             // ds_write_b128, conflict-free
        }
        __syncthreads();                              // B1: pexA visible

        // ---- b: upd1 (reads pexA; stale entries only where mbit=0 -> discarded)
        {
            float hs = pexA[0][j] + pexA[1][j] + pexA[2][j] + pexA[3][j];
            float h1 = hs + fmaf(xls[t], wi1, bs1);
            upd(mem1, sp1, h1, mbit);
            bal1 = __ballot(sp1 != 0.0f);
        }
        // ---- c: L2 partials = spk1_new @ W2a^T + spk2_old @ W2b^T
        if (act) {
            float4 a = {0.f, 0.f, 0.f, 0.f};
            consume64(wt2a, bal1, l16, a);
            consume64(wt2b, bal2, l16, a);
            ((float4*)pexB[w])[lane] = a;
        }
        __syncthreads();                              // B2: pexB visible

        // ---- d: upd2
        {
            float hs = pexB[0][j] + pexB[1][j] + pexB[2][j] + pexB[3][j];
            upd(mem2, sp2, hs + bs2, mbit);
            bal2 = __ballot(sp2 != 0.0f);
        }
        // ---- e: L3 partials = spk2_new @ W3^T
        if (act) {
            float4 a = {0.f, 0.f, 0.f, 0.f};
            consume64(wt3, bal2, l16, a);
            ((float4*)pexC[w])[lane] = a;
        }
        __syncthreads();                              // B3: pexC visible

        // ---- f: upd3 + spike count (next a rewrites pexA: its last read was
        // phase b, ≥2 barriers back for every wave — safe, as in R6)
        {
            float hs = pexC[0][j] + pexC[1][j] + pexC[2][j] + pexC[3][j];
            upd(mem3, sp3, hs + bs3, mbit);
            cnt += sp3;
        }

        ph++; if (ph == mc) ph = 0;
    }

    // ---- output: out[s][i] = (sum_j w_h2o3[i][j]*cnt_j)/784 + b[i]
    #pragma unroll
    for (int i = 0; i < 10; i++) {
        float v = cnt * w_h2o3[i * H + j];
        for (int off = 32; off; off >>= 1) v += __shfl_down(v, off, 64);
        if (lane == 0) wred[w][i] = v;
    }
    __syncthreads();
    if (tid < 10) {
        float sum = wred[0][tid] + wred[1][tid] + wred[2][tid] + wred[3][tid];
        out[(size_t)s * 10 + tid] = sum / 784.0f + b_h2o3[tid];
    }
}

extern "C" void kernel_launch(void* const* d_in, const int* in_sizes, int n_in,
                              void* d_out, int out_size, void* d_ws, size_t ws_size,
                              hipStream_t stream) {
    (void)in_sizes; (void)n_in; (void)ws_size; (void)out_size;
    const float* x      = (const float*)d_in[0];
    const float* w_i2h1 = (const float*)d_in[1];
    const float* b_i2h1 = (const float*)d_in[2];
    const float* w_h2h1 = (const float*)d_in[3];
    const float* b_h2h1 = (const float*)d_in[4];
    const float* w_i2h2 = (const float*)d_in[5];
    const float* b_i2h2 = (const float*)d_in[6];
    const float* w_h2h2 = (const float*)d_in[7];
    const float* b_h2h2 = (const float*)d_in[8];
    const float* w_i2h3 = (const float*)d_in[9];
    const float* b_i2h3 = (const float*)d_in[10];
    const float* w_h2o3 = (const float*)d_in[11];
    const float* b_h2o3 = (const float*)d_in[12];
    float* ws = (float*)d_ws;   // 4 * 256 KB = 1 MB

    prep_transpose<<<64, 256, 0, stream>>>(w_h2h1, w_i2h2, w_h2h2, w_i2h3, ws);
    srnn_kernel<<<NBLK, NTHR, 0, stream>>>(x,
        w_i2h1, b_i2h1, b_h2h1,
        b_i2h2, b_h2h2, b_i2h3,
        w_h2o3, b_h2o3, ws,
        (float*)d_out);
}

// Round 9
// 1999.193 us; speedup vs baseline: 1.4437x; 1.1307x over previous
//
#include <hip/hip_runtime.h>
#include <stdint.h>

#define T_STEPS 784
#define H 256
#define NBLK 512        // 1 sample per block, 2 blocks/CU
#define NTHR 256        // 4 waves; wave w owns neurons AND rows [64w, 64w+64)

typedef unsigned long long u64;
typedef unsigned int u32;

// Per-neuron mask parameters, replicating numpy linspace/ceil/round in float64.
__device__ __forceinline__ void mask_params(int j, int& c, int& on, int& ps) {
    const double stepc = (8.0 - 4.0) / 255.0;
    const double stepd = (0.9 - 0.1) / 255.0;
    const double stepp = 4.0 / 255.0;
    double cyc = (j == 255) ? 8.0 : __dadd_rn(__dmul_rn((double)j, stepc), 4.0);
    c = (int)ceil(cyc);
    double dc  = (j == 255) ? 0.9 : __dadd_rn(__dmul_rn((double)j, stepd), 0.1);
    on = (int)ceil(__dmul_rn(dc, (double)c));
    double psd = (j == 255) ? 4.0 : __dmul_rn((double)j, stepp);
    ps = (int)rint(psd);
}

__device__ __forceinline__ void acc_add(const float4& w, float4& a) {
    a.x += w.x; a.y += w.y; a.z += w.z; a.w += w.w;
}

// Sparse accumulate over this wave's 64 rows. m: wave's own spike ballot (SGPR,
// loop-carried in registers). base: rows [64w..64w+64) (row k -> 1KB apart);
// lane covers 4 cols via l16. 8-deep load batching; binary tail.
__device__ __forceinline__ void consume64(const char* __restrict__ base, u64 m,
                                          int l16, float4& acc) {
    int n = __popcll(m);
    while (n >= 8) {
        int k0=__builtin_ctzll(m); m&=m-1; int k1=__builtin_ctzll(m); m&=m-1;
        int k2=__builtin_ctzll(m); m&=m-1; int k3=__builtin_ctzll(m); m&=m-1;
        int k4=__builtin_ctzll(m); m&=m-1; int k5=__builtin_ctzll(m); m&=m-1;
        int k6=__builtin_ctzll(m); m&=m-1; int k7=__builtin_ctzll(m); m&=m-1;
        float4 w0 = *(const float4*)(base + (k0<<10) + l16);
        float4 w1 = *(const float4*)(base + (k1<<10) + l16);
        float4 w2 = *(const float4*)(base + (k2<<10) + l16);
        float4 w3 = *(const float4*)(base + (k3<<10) + l16);
        float4 w4 = *(const float4*)(base + (k4<<10) + l16);
        float4 w5 = *(const float4*)(base + (k5<<10) + l16);
        float4 w6 = *(const float4*)(base + (k6<<10) + l16);
        float4 w7 = *(const float4*)(base + (k7<<10) + l16);
        acc_add(w0, acc); acc_add(w1, acc); acc_add(w2, acc); acc_add(w3, acc);
        acc_add(w4, acc); acc_add(w5, acc); acc_add(w6, acc); acc_add(w7, acc);
        n -= 8;
    }
    if (n & 4) {
        int k0=__builtin_ctzll(m); m&=m-1; int k1=__builtin_ctzll(m); m&=m-1;
        int k2=__builtin_ctzll(m); m&=m-1; int k3=__builtin_ctzll(m); m&=m-1;
        float4 w0 = *(const float4*)(base + (k0<<10) + l16);
        float4 w1 = *(const float4*)(base + (k1<<10) + l16);
        float4 w2 = *(const float4*)(base + (k2<<10) + l16);
        float4 w3 = *(const float4*)(base + (k3<<10) + l16);
        acc_add(w0, acc); acc_add(w1, acc); acc_add(w2, acc); acc_add(w3, acc);
    }
    if (n & 2) {
        int k0=__builtin_ctzll(m); m&=m-1; int k1=__builtin_ctzll(m); m&=m-1;
        float4 w0 = *(const float4*)(base + (k0<<10) + l16);
        float4 w1 = *(const float4*)(base + (k1<<10) + l16);
        acc_add(w0, acc); acc_add(w1, acc);
    }
    if (n & 1) {
        int k0 = __builtin_ctzll(m);
        float4 w0 = *(const float4*)(base + (k0<<10) + l16);
        acc_add(w0, acc);
    }
}

__device__ __forceinline__ void upd(float& mem, float& sp, float h, int mbit) {
    float nm = fmaf(mem * 0.5f, (1.0f - sp), h);
    mem = mbit ? nm : mem;
    sp  = (mbit && (mem > 0.5f)) ? 1.0f : 0.0f;
}

// Tiled transpose of the 4 weight matrices into ws: WT[k][j] = W[j][k].
__global__ __launch_bounds__(256)
void prep_transpose(const float* __restrict__ w1, const float* __restrict__ w2a,
                    const float* __restrict__ w2b, const float* __restrict__ w3,
                    float* __restrict__ ws)
{
    __shared__ float tile[64][65];
    const int bid = blockIdx.x;                 // 64 blocks: m(4) x kt(4) x jt(4)
    const int m  = bid >> 4;
    const int kt = (bid >> 2) & 3;
    const int jt = bid & 3;
    const float* src = (m == 0) ? w1 : (m == 1) ? w2a : (m == 2) ? w2b : w3;
    float* dst = ws + (size_t)m * H * H;
    const int tid = threadIdx.x;
    const int c = tid & 63, r4 = tid >> 6;
    #pragma unroll
    for (int rr = 0; rr < 16; rr++) {
        int r = r4 * 16 + rr;
        tile[r][c] = src[(size_t)(jt * 64 + r) * H + kt * 64 + c];
    }
    __syncthreads();
    #pragma unroll
    for (int rr = 0; rr < 16; rr++) {
        int r = r4 * 16 + rr;
        dst[(size_t)(kt * 64 + r) * H + jt * 64 + c] = tile[c][r];
    }
}

__global__ __launch_bounds__(NTHR, 2)
void srnn_kernel(const float* __restrict__ x,
                 const float* __restrict__ w_i2h1, const float* __restrict__ b_i2h1,
                 const float* __restrict__ b_h2h1,
                 const float* __restrict__ b_i2h2, const float* __restrict__ b_h2h2,
                 const float* __restrict__ b_i2h3,
                 const float* __restrict__ w_h2o3, const float* __restrict__ b_h2o3,
                 const float* __restrict__ ws,     // WT1 | WT2a | WT2b | WT3
                 float* __restrict__ out)
{
    const int tid  = threadIdx.x;
    const int lane = tid & 63;
    const int w    = tid >> 6;         // wave id = j-group = row-group
    const int j    = tid;              // this thread's neuron
    const int l16  = lane * 16;        // byte offset into each row (4 cols/lane)
    const int s    = blockIdx.x;       // sample

    // Wave's row-slice base per matrix: rows [64w, 64w+64), 64KB per slice.
    const char* wt1  = (const char*)ws + (0 << 18) + (w << 16);
    const char* wt2a = (const char*)ws + (1 << 18) + (w << 16);
    const char* wt2b = (const char*)ws + (2 << 18) + (w << 16);
    const char* wt3  = (const char*)ws + (3 << 18) + (w << 16);

    __shared__ float xls[T_STEPS];          // 3.1 KB
    __shared__ float pexA[4][H];            // W1-recurrent partials (for h1 of t+1)
    __shared__ float pexB[4][H];            // h2 partials
    __shared__ float pexC[4][H];            // h3 partials
    __shared__ float wred[4][10];

    for (int i = tid; i < T_STEPS; i += NTHR)
        xls[i] = x[(size_t)s * T_STEPS + i];
    // zero pexA/pexC: read by the first Region1 before being written
    #pragma unroll
    for (int q = 0; q < 4; q++) { pexA[q][j] = 0.f; pexC[q][j] = 0.f; }

    int mc, mon, mps;
    mask_params(j, mc, mon, mps);
    int ph = (mc - (mps % mc)) % mc;

    const float bs1 = b_i2h1[j] + b_h2h1[j];
    const float bs2 = b_i2h2[j] + b_h2h2[j];
    const float bs3 = b_i2h3[j];
    const float wi1 = w_i2h1[j];

    float mem1 = 0.f, mem2 = 0.f, mem3 = 0.f;
    float sp1 = 0.f, sp2 = 0.f, sp3 = 0.f;
    u64 bal1 = 0ull, bal2 = 0ull;      // this wave's spike masks, register-resident
    float cnt = 0.f;                   // sum_t spk3; out = wo·cnt at end (exact)
    int mbit_prev = 0;                 // mask bit of step t-1 (for deferred upd3)

    __syncthreads();

    // Pipelined loop: iteration t does
    //  Region1: [W2b(bal2(t-1)) loads ∥ upd3(t-1), upd1(t)] + W2a(bal1(t)) -> pexB
    //  Region2: [W1(bal1(t)) loads ∥ upd2(t)] + W3(bal2(t)) -> pexA, pexC
    for (int t = 0; t < T_STEPS; t++) {
        const int mbit = (ph < mon) ? 1 : 0;

        // ======== Region 1 ========
        {
            // issue W2b loads first (bal2 = spk2(t-1), known) — fly under upds
            float4 accB = {0.f, 0.f, 0.f, 0.f};
            // LDS partial reads for both upds (latency overlaps W2b loads)
            float cA0 = pexA[0][j], cA1 = pexA[1][j], cA2 = pexA[2][j], cA3 = pexA[3][j];
            float cC0 = pexC[0][j], cC1 = pexC[1][j], cC2 = pexC[2][j], cC3 = pexC[3][j];
            consume64(wt2b, bal2, l16, accB);
            // upd3(t-1)
            upd(mem3, sp3, (cC0 + cC1) + (cC2 + cC3) + bs3, mbit_prev);
            cnt += sp3;
            // upd1(t)
            float h1 = (cA0 + cA1) + (cA2 + cA3) + fmaf(xls[t], wi1, bs1);
            upd(mem1, sp1, h1, mbit);
            bal1 = __ballot(sp1 != 0.0f);
            // W2a gated by fresh spk1(t)
            consume64(wt2a, bal1, l16, accB);
            ((float4*)pexB[w])[lane] = accB;          // ds_write_b128, conflict-free
        }
        __syncthreads();                              // BAR1: pexB visible

        // ======== Region 2 ========
        {
            // issue W1 loads first (bal1 known) — fly under upd2
            float4 accA = {0.f, 0.f, 0.f, 0.f};
            float bB0 = pexB[0][j], bB1 = pexB[1][j], bB2 = pexB[2][j], bB3 = pexB[3][j];
            consume64(wt1, bal1, l16, accA);
            // upd2(t)
            upd(mem2, sp2, (bB0 + bB1) + (bB2 + bB3) + bs2, mbit);
            bal2 = __ballot(sp2 != 0.0f);
            // W3 gated by fresh spk2(t)
            float4 accC = {0.f, 0.f, 0.f, 0.f};
            consume64(wt3, bal2, l16, accC);
            ((float4*)pexA[w])[lane] = accA;
            ((float4*)pexC[w])[lane] = accC;
        }
        __syncthreads();                              // BAR2: pexA/pexC visible

        mbit_prev = mbit;
        ph++; if (ph == mc) ph = 0;
    }

    // ---- tail: upd3(T-1) (pexC from last Region2, after BAR2)
    {
        float cC0 = pexC[0][j], cC1 = pexC[1][j], cC2 = pexC[2][j], cC3 = pexC[3][j];
        upd(mem3, sp3, (cC0 + cC1) + (cC2 + cC3) + bs3, mbit_prev);
        cnt += sp3;
    }

    // ---- output: out[s][i] = (sum_j w_h2o3[i][j]*cnt_j)/784 + b[i]
    #pragma unroll
    for (int i = 0; i < 10; i++) {
        float v = cnt * w_h2o3[i * H + j];
        for (int off = 32; off; off >>= 1) v += __shfl_down(v, off, 64);
        if (lane == 0) wred[w][i] = v;
    }
    __syncthreads();
    if (tid < 10) {
        float sum = wred[0][tid] + wred[1][tid] + wred[2][tid] + wred[3][tid];
        out[(size_t)s * 10 + tid] = sum / 784.0f + b_h2o3[tid];
    }
}

extern "C" void kernel_launch(void* const* d_in, const int* in_sizes, int n_in,
                              void* d_out, int out_size, void* d_ws, size_t ws_size,
                              hipStream_t stream) {
    (void)in_sizes; (void)n_in; (void)ws_size; (void)out_size;
    const float* x      = (const float*)d_in[0];
    const float* w_i2h1 = (const float*)d_in[1];
    const float* b_i2h1 = (const float*)d_in[2];
    const float* w_h2h1 = (const float*)d_in[3];
    const float* b_h2h1 = (const float*)d_in[4];
    const float* w_i2h2 = (const float*)d_in[5];
    const float* b_i2h2 = (const float*)d_in[6];
    const float* w_h2h2 = (const float*)d_in[7];
    const float* b_h2h2 = (const float*)d_in[8];
    const float* w_i2h3 = (const float*)d_in[9];
    const float* b_i2h3 = (const float*)d_in[10];
    const float* w_h2o3 = (const float*)d_in[11];
    const float* b_h2o3 = (const float*)d_in[12];
    float* ws = (float*)d_ws;   // 4 * 256 KB = 1 MB

    prep_transpose<<<64, 256, 0, stream>>>(w_h2h1, w_i2h2, w_h2h2, w_i2h3, ws);
    srnn_kernel<<<NBLK, NTHR, 0, stream>>>(x,
        w_i2h1, b_i2h1, b_h2h1,
        b_i2h2, b_h2h2, b_i2h3,
        w_h2o3, b_h2o3, ws,
        (float*)d_out);
}